// Round 1
// baseline (1271.323 us; speedup 1.0000x reference)
//
#include <hip/hip_runtime.h>
#include <hip/hip_bf16.h>
#include <math.h>

#define NA 50000
#define NS 5000
#define E_AA 500000
#define E_AS 250000
#define CDIM 128
#define ED 8

// ---------------- CSR build ----------------

__global__ void count_k(const int* __restrict__ dst, int E, int* __restrict__ deg) {
    int e = blockIdx.x * blockDim.x + threadIdx.x;
    if (e < E) atomicAdd(&deg[dst[e]], 1);
}

__global__ __launch_bounds__(1024) void scan_k(const int* __restrict__ deg,
                                               int* __restrict__ row_start, int n) {
    int t = threadIdx.x;
    int per = (n + 1023) / 1024;
    int s0 = t * per;
    int s1 = s0 + per; if (s1 > n) s1 = n;
    int sum = 0;
    for (int i = s0; i < s1; ++i) sum += deg[i];
    __shared__ int wsum[16];
    int lane = t & 63, w = t >> 6;
    int v = sum;
    #pragma unroll
    for (int off = 1; off < 64; off <<= 1) {
        int u = __shfl_up(v, off, 64);
        if (lane >= off) v += u;
    }
    if (lane == 63) wsum[w] = v;
    __syncthreads();
    if (w == 0 && lane < 16) {
        int wv = wsum[lane];
        #pragma unroll
        for (int off = 1; off < 16; off <<= 1) {
            int u = __shfl_up(wv, off, 64);
            if (lane >= off) wv += u;
        }
        wsum[lane] = wv;
    }
    __syncthreads();
    int waveoff = (w > 0) ? wsum[w - 1] : 0;
    int excl = waveoff + v - sum;   // exclusive prefix of this thread's slice
    int run = excl;
    for (int i = s0; i < s1; ++i) { row_start[i] = run; run += deg[i]; }
    if (t == 1023) row_start[n] = run;   // total
}

__global__ void scatter_k(const int* __restrict__ dst, int E,
                          const int* __restrict__ row_start,
                          int* __restrict__ cursor, int* __restrict__ csr) {
    int e = blockIdx.x * blockDim.x + threadIdx.x;
    if (e < E) {
        int d = dst[e];
        int pos = atomicAdd(&cursor[d], 1);
        csr[row_start[d] + pos] = e;
    }
}

// ---------------- GEMM: Y[N,128] = X[N,K] @ W[K,128], f32 ----------------

template<int K>
__global__ __launch_bounds__(256) void gemm_k(const float* __restrict__ X,
                                              const float* __restrict__ W,
                                              float* __restrict__ Y, int N) {
    __shared__ float Ws[64 * 128];    // one 64-row chunk of W  (32 KB)
    __shared__ float Xs[32 * K];      // 32-row X tile          (16 KB @K=128)
    int t = threadIdx.x;
    int rbase = blockIdx.x * 32;

    // load X tile (float4)
    const int K4 = K / 4;
    const float4* X4 = (const float4*)X;
    float4* Xs4 = (float4*)Xs;
    for (int i = t; i < 32 * K4; i += 256) {
        int r = i / K4, c4 = i % K4;
        int row = rbase + r;
        float4 v = make_float4(0.f, 0.f, 0.f, 0.f);
        if (row < N) v = X4[(size_t)row * K4 + c4];
        Xs4[i] = v;
    }

    int cg = t & 31;      // col group: cols [cg*4, cg*4+4)
    int rq = t >> 5;      // 0..7 ; rows rq + 8*i, i=0..3
    float4 acc[4] = {};
    float4* Ws4 = (float4*)Ws;
    const float4* W4 = (const float4*)W;

    for (int kb = 0; kb < K; kb += 64) {
        __syncthreads();
        // load W chunk rows [kb, kb+64): 64*128/4 = 2048 float4
        for (int i = t; i < 2048; i += 256) Ws4[i] = W4[(size_t)kb * 32 + i];
        __syncthreads();
        #pragma unroll 8
        for (int k2 = 0; k2 < 64; ++k2) {
            float4 w = Ws4[k2 * 32 + cg];
            int k = kb + k2;
            #pragma unroll
            for (int i = 0; i < 4; ++i) {
                float x = Xs[(rq + 8 * i) * K + k];
                acc[i].x += x * w.x; acc[i].y += x * w.y;
                acc[i].z += x * w.z; acc[i].w += x * w.w;
            }
        }
    }
    #pragma unroll
    for (int i = 0; i < 4; ++i) {
        int row = rbase + rq + 8 * i;
        if (row < N) ((float4*)Y)[(size_t)row * 32 + cg] = acc[i];
    }
}

// ---------------- fused GATv2 aggregation (one wave per dst node) ----------------
// online softmax over incoming edges; epilogue: +bias, optional relu, L2 norm

template<bool RELU>
__global__ __launch_bounds__(256) void agg_k(
    const float* __restrict__ xl, const float* __restrict__ xr,
    const float* __restrict__ eattr, const int* __restrict__ srcv,
    const float* __restrict__ We, const float* __restrict__ att,
    const float* __restrict__ bias, const int* __restrict__ row_start,
    const int* __restrict__ csr_eid, float* __restrict__ out, int ndst) {
    int wave = threadIdx.x >> 6;
    int lane = threadIdx.x & 63;
    int d = blockIdx.x * 4 + wave;
    if (d >= ndst) return;
    int c = lane * 2;

    float2 We2[8];
    #pragma unroll
    for (int k = 0; k < 8; ++k) We2[k] = *(const float2*)(We + k * 128 + c);
    float2 att2 = *(const float2*)(att + c);
    float2 b2   = *(const float2*)(bias + c);
    float2 xr2  = *(const float2*)(xr + (size_t)d * 128 + c);

    float2 acc = {0.f, 0.f};
    float den = 0.f, mrun = -INFINITY;

    int e0 = row_start[d], e1 = row_start[d + 1];
    for (int i = e0; i < e1; ++i) {
        int eid = csr_eid[i];
        int s = srcv[eid];
        const float* ea = eattr + (size_t)eid * 8;
        float2 xls = *(const float2*)(xl + (size_t)s * 128 + c);
        float2 m = {xls.x + xr2.x, xls.y + xr2.y};
        #pragma unroll
        for (int k = 0; k < 8; ++k) {
            float a = ea[k];
            m.x += a * We2[k].x;
            m.y += a * We2[k].y;
        }
        float mx = m.x > 0.f ? m.x : 0.2f * m.x;
        float my = m.y > 0.f ? m.y : 0.2f * m.y;
        float tt = mx * att2.x + my * att2.y;
        #pragma unroll
        for (int off = 32; off; off >>= 1) tt += __shfl_xor(tt, off, 64);
        // online softmax update (uniform across wave)
        float nm = fmaxf(mrun, tt);
        float sc = __expf(mrun - nm);
        float p  = __expf(tt - nm);
        den = den * sc + p;
        acc.x = acc.x * sc + p * xls.x;
        acc.y = acc.y * sc + p * xls.y;
        mrun = nm;
    }

    float inv = 1.f / fmaxf(den, 1e-16f);
    float ox = acc.x * inv + b2.x;
    float oy = acc.y * inv + b2.y;
    if (RELU) { ox = fmaxf(ox, 0.f); oy = fmaxf(oy, 0.f); }
    float ss = ox * ox + oy * oy;
    #pragma unroll
    for (int off = 32; off; off >>= 1) ss += __shfl_xor(ss, off, 64);
    float nrm = sqrtf(ss);
    float innv = 1.f / fmaxf(nrm, 1e-12f);
    out[(size_t)d * 128 + c]     = ox * innv;
    out[(size_t)d * 128 + c + 1] = oy * innv;
}

// ---------------- launch ----------------

extern "C" void kernel_launch(void* const* d_in, const int* in_sizes, int n_in,
                              void* d_out, int out_size, void* d_ws, size_t ws_size,
                              hipStream_t stream) {
    const float* x_artist = (const float*)d_in[0];
    const float* x_style  = (const float*)d_in[1];
    const int*   src_aa   = (const int*)d_in[2];
    const int*   dst_aa   = (const int*)d_in[3];
    const float* eattr_aa = (const float*)d_in[4];
    const int*   src_as   = (const int*)d_in[5];
    const int*   dst_as   = (const int*)d_in[6];
    const float* eattr_as = (const float*)d_in[7];
    const float* Wl0_aa = (const float*)d_in[8];
    const float* Wr0_aa = (const float*)d_in[9];
    const float* att0_aa = (const float*)d_in[10];
    const float* We0_aa = (const float*)d_in[11];
    const float* b0_aa = (const float*)d_in[12];
    const float* Wl0_as = (const float*)d_in[13];
    const float* Wr0_as = (const float*)d_in[14];
    const float* att0_as = (const float*)d_in[15];
    const float* We0_as = (const float*)d_in[16];
    const float* b0_as = (const float*)d_in[17];
    const float* Wl_aa = (const float*)d_in[18];
    const float* Wr_aa = (const float*)d_in[19];
    const float* att_aa = (const float*)d_in[20];
    const float* We_aa = (const float*)d_in[21];
    const float* b_aa = (const float*)d_in[22];
    const float* Wl_as = (const float*)d_in[23];
    const float* Wr_as = (const float*)d_in[24];
    const float* att_as = (const float*)d_in[25];
    const float* We_as = (const float*)d_in[26];
    const float* b_as = (const float*)d_in[27];

    float* out = (float*)d_out;

    // workspace layout (floats then ints)
    size_t off = 0;
    auto allocf = [&](size_t n) { float* r = (float*)d_ws + off; off += n; return r; };
    float* hA0 = allocf((size_t)NA * CDIM);
    float* hA1 = allocf((size_t)NA * CDIM);
    float* hS0 = allocf((size_t)NS * CDIM);
    float* hS1 = allocf((size_t)NS * CDIM);
    float* bufA = allocf((size_t)NA * CDIM);   // xl (both edge types)
    float* bufB = allocf((size_t)NA * CDIM);   // xr_aa
    float* bufC = allocf((size_t)NS * CDIM);   // xr_as
    int* ip = (int*)((float*)d_ws + off);
    int* rs_aa  = ip;            ip += NA + 1;
    int* cur_aa = ip;            ip += NA;
    int* csr_aa = ip;            ip += E_AA;
    int* rs_as  = ip;            ip += NS + 1;
    int* cur_as = ip;            ip += NS;
    int* csr_as = ip;            ip += E_AS;

    // ---- build CSR (same every call; inputs are fixed) ----
    hipMemsetAsync(cur_aa, 0, NA * sizeof(int), stream);
    count_k<<<(E_AA + 255) / 256, 256, 0, stream>>>(dst_aa, E_AA, cur_aa);
    scan_k<<<1, 1024, 0, stream>>>(cur_aa, rs_aa, NA);
    hipMemsetAsync(cur_aa, 0, NA * sizeof(int), stream);
    scatter_k<<<(E_AA + 255) / 256, 256, 0, stream>>>(dst_aa, E_AA, rs_aa, cur_aa, csr_aa);

    hipMemsetAsync(cur_as, 0, NS * sizeof(int), stream);
    count_k<<<(E_AS + 255) / 256, 256, 0, stream>>>(dst_as, E_AS, cur_as);
    scan_k<<<1, 1024, 0, stream>>>(cur_as, rs_as, NS);
    hipMemsetAsync(cur_as, 0, NS * sizeof(int), stream);
    scatter_k<<<(E_AS + 255) / 256, 256, 0, stream>>>(dst_as, E_AS, rs_as, cur_as, csr_as);

    const int gA = (NA + 31) / 32;      // gemm grid for NA rows
    const int gS = (NS + 31) / 32;
    const int aggA = (NA + 3) / 4;
    const int aggS = (NS + 3) / 4;

    const float* hA_in = x_artist;
    const float* hS_in = x_style;

    for (int layer = 0; layer < 3; ++layer) {
        int j = layer - 1;
        const float *pWl_aa, *pWr_aa, *patt_aa, *pWe_aa, *pb_aa;
        const float *pWl_as, *pWr_as, *patt_as, *pWe_as, *pb_as;
        if (layer == 0) {
            pWl_aa = Wl0_aa; pWr_aa = Wr0_aa; patt_aa = att0_aa; pWe_aa = We0_aa; pb_aa = b0_aa;
            pWl_as = Wl0_as; pWr_as = Wr0_as; patt_as = att0_as; pWe_as = We0_as; pb_as = b0_as;
        } else {
            pWl_aa = Wl_aa + (size_t)j * CDIM * CDIM;
            pWr_aa = Wr_aa + (size_t)j * CDIM * CDIM;
            patt_aa = att_aa + (size_t)j * CDIM;
            pWe_aa = We_aa + (size_t)j * ED * CDIM;
            pb_aa = b_aa + (size_t)j * CDIM;
            pWl_as = Wl_as + (size_t)j * CDIM * CDIM;
            pWr_as = Wr_as + (size_t)j * CDIM * CDIM;
            patt_as = att_as + (size_t)j * CDIM;
            pWe_as = We_as + (size_t)j * ED * CDIM;
            pb_as = b_as + (size_t)j * CDIM;
        }
        float* hA_out = (layer == 2) ? out : (layer == 0 ? hA0 : hA1);
        float* hS_out = (layer == 2) ? out + (size_t)NA * CDIM : (layer == 0 ? hS0 : hS1);

        // ---- artist -> artist ----
        gemm_k<128><<<gA, 256, 0, stream>>>(hA_in, pWl_aa, bufA, NA);
        gemm_k<128><<<gA, 256, 0, stream>>>(hA_in, pWr_aa, bufB, NA);
        if (layer < 2)
            agg_k<true><<<aggA, 256, 0, stream>>>(bufA, bufB, eattr_aa, src_aa, pWe_aa,
                                                  patt_aa, pb_aa, rs_aa, csr_aa, hA_out, NA);
        else
            agg_k<false><<<aggA, 256, 0, stream>>>(bufA, bufB, eattr_aa, src_aa, pWe_aa,
                                                   patt_aa, pb_aa, rs_aa, csr_aa, hA_out, NA);

        // ---- artist -> style ----
        gemm_k<128><<<gA, 256, 0, stream>>>(hA_in, pWl_as, bufA, NA);
        if (layer == 0)
            gemm_k<64><<<gS, 256, 0, stream>>>(hS_in, pWr_as, bufC, NS);
        else
            gemm_k<128><<<gS, 256, 0, stream>>>(hS_in, pWr_as, bufC, NS);
        if (layer < 2)
            agg_k<true><<<aggS, 256, 0, stream>>>(bufA, bufC, eattr_as, src_as, pWe_as,
                                                  patt_as, pb_as, rs_as, csr_as, hS_out, NS);
        else
            agg_k<false><<<aggS, 256, 0, stream>>>(bufA, bufC, eattr_as, src_as, pWe_as,
                                                   patt_as, pb_as, rs_as, csr_as, hS_out, NS);

        hA_in = hA_out;
        hS_in = hS_out;
    }
}

// Round 2
// 1080.793 us; speedup vs baseline: 1.1763x; 1.1763x over previous
//
#include <hip/hip_runtime.h>
#include <hip/hip_bf16.h>
#include <math.h>

#define NA 50000
#define NS 5000
#define E_AA 500000
#define E_AS 250000
#define CDIM 128
#define ED 8

// ---------------- CSR build ----------------

__global__ void count_k(const int* __restrict__ dst, int E, int* __restrict__ deg) {
    int e = blockIdx.x * blockDim.x + threadIdx.x;
    if (e < E) atomicAdd(&deg[dst[e]], 1);
}

__global__ __launch_bounds__(1024) void scan_k(const int* __restrict__ deg,
                                               int* __restrict__ row_start, int n) {
    int t = threadIdx.x;
    int per = (n + 1023) / 1024;
    int s0 = t * per;
    int s1 = s0 + per; if (s1 > n) s1 = n;
    int sum = 0;
    for (int i = s0; i < s1; ++i) sum += deg[i];
    __shared__ int wsum[16];
    int lane = t & 63, w = t >> 6;
    int v = sum;
    #pragma unroll
    for (int off = 1; off < 64; off <<= 1) {
        int u = __shfl_up(v, off, 64);
        if (lane >= off) v += u;
    }
    if (lane == 63) wsum[w] = v;
    __syncthreads();
    if (w == 0 && lane < 16) {
        int wv = wsum[lane];
        #pragma unroll
        for (int off = 1; off < 16; off <<= 1) {
            int u = __shfl_up(wv, off, 64);
            if (lane >= off) wv += u;
        }
        wsum[lane] = wv;
    }
    __syncthreads();
    int waveoff = (w > 0) ? wsum[w - 1] : 0;
    int excl = waveoff + v - sum;
    int run = excl;
    for (int i = s0; i < s1; ++i) { row_start[i] = run; run += deg[i]; }
    if (t == 1023) row_start[n] = run;
}

__global__ void scatter_k(const int* __restrict__ dst, int E,
                          const int* __restrict__ row_start,
                          int* __restrict__ cursor, int* __restrict__ csr) {
    int e = blockIdx.x * blockDim.x + threadIdx.x;
    if (e < E) {
        int d = dst[e];
        int pos = atomicAdd(&cursor[d], 1);
        csr[row_start[d] + pos] = e;
    }
}

// ---------------- single GEMM: Y[N,128] = X[N,K] @ W[K,128], f32 ----------------

template<int K>
__global__ __launch_bounds__(256) void gemm_k(const float* __restrict__ X,
                                              const float* __restrict__ W,
                                              float* __restrict__ Y, int N) {
    __shared__ float Ws[64 * 128];
    __shared__ float Xs[32 * K];
    int t = threadIdx.x;
    int rbase = blockIdx.x * 32;

    const int K4 = K / 4;
    const float4* X4 = (const float4*)X;
    float4* Xs4 = (float4*)Xs;
    for (int i = t; i < 32 * K4; i += 256) {
        int r = i / K4, c4 = i % K4;
        int row = rbase + r;
        float4 v = make_float4(0.f, 0.f, 0.f, 0.f);
        if (row < N) v = X4[(size_t)row * K4 + c4];
        Xs4[i] = v;
    }

    int cg = t & 31;
    int rq = t >> 5;
    float4 acc[4] = {};
    float4* Ws4 = (float4*)Ws;
    const float4* W4 = (const float4*)W;

    for (int kb = 0; kb < K; kb += 64) {
        __syncthreads();
        for (int i = t; i < 2048; i += 256) Ws4[i] = W4[(size_t)kb * 32 + i];
        __syncthreads();
        #pragma unroll 8
        for (int k2 = 0; k2 < 64; ++k2) {
            float4 w = Ws4[k2 * 32 + cg];
            int k = kb + k2;
            #pragma unroll
            for (int i = 0; i < 4; ++i) {
                float x = Xs[(rq + 8 * i) * K + k];
                acc[i].x += x * w.x; acc[i].y += x * w.y;
                acc[i].z += x * w.z; acc[i].w += x * w.w;
            }
        }
    }
    #pragma unroll
    for (int i = 0; i < 4; ++i) {
        int row = rbase + rq + 8 * i;
        if (row < N) ((float4*)Y)[(size_t)row * 32 + cg] = acc[i];
    }
}

// ---------------- fused triple GEMM (same X, K=128): Yi = X @ Wi ----------------

__global__ __launch_bounds__(256) void gemm3_k(const float* __restrict__ X,
                                               const float* __restrict__ W0,
                                               const float* __restrict__ W1,
                                               const float* __restrict__ W2,
                                               float* __restrict__ Y0,
                                               float* __restrict__ Y1,
                                               float* __restrict__ Y2, int N) {
    __shared__ float Ws[64 * 128];
    __shared__ float Xs[32 * 128];
    int t = threadIdx.x;
    int rbase = blockIdx.x * 32;

    const float4* X4 = (const float4*)X;
    float4* Xs4 = (float4*)Xs;
    for (int i = t; i < 32 * 32; i += 256) {
        int r = i / 32, c4 = i % 32;
        int row = rbase + r;
        float4 v = make_float4(0.f, 0.f, 0.f, 0.f);
        if (row < N) v = X4[(size_t)row * 32 + c4];
        Xs4[i] = v;
    }

    int cg = t & 31;
    int rq = t >> 5;
    float4* Ws4 = (float4*)Ws;

    const float* Wp[3] = {W0, W1, W2};
    float* Yp[3] = {Y0, Y1, Y2};

    for (int w = 0; w < 3; ++w) {
        const float4* W4 = (const float4*)Wp[w];
        float4 acc[4] = {};
        for (int kb = 0; kb < 128; kb += 64) {
            __syncthreads();   // also protects Xs on first pass / Ws reuse across passes
            for (int i = t; i < 2048; i += 256) Ws4[i] = W4[(size_t)kb * 32 + i];
            __syncthreads();
            #pragma unroll 8
            for (int k2 = 0; k2 < 64; ++k2) {
                float4 wv = Ws4[k2 * 32 + cg];
                int k = kb + k2;
                #pragma unroll
                for (int i = 0; i < 4; ++i) {
                    float x = Xs[(rq + 8 * i) * 128 + k];
                    acc[i].x += x * wv.x; acc[i].y += x * wv.y;
                    acc[i].z += x * wv.z; acc[i].w += x * wv.w;
                }
            }
        }
        #pragma unroll
        for (int i = 0; i < 4; ++i) {
            int row = rbase + rq + 8 * i;
            if (row < N) ((float4*)Yp[w])[(size_t)row * 32 + cg] = acc[i];
        }
    }
}

// ---------------- fused GATv2 aggregation, 4-edge ILP unroll ----------------

template<bool RELU>
__global__ __launch_bounds__(256) void agg_k(
    const float* __restrict__ xl, const float* __restrict__ xr,
    const float* __restrict__ eattr, const int* __restrict__ srcv,
    const float* __restrict__ We, const float* __restrict__ att,
    const float* __restrict__ bias, const int* __restrict__ row_start,
    const int* __restrict__ csr_eid, float* __restrict__ out, int ndst) {
    int wave = threadIdx.x >> 6;
    int lane = threadIdx.x & 63;
    int d = blockIdx.x * 4 + wave;
    if (d >= ndst) return;
    int c = lane * 2;

    float2 We2[8];
    #pragma unroll
    for (int k = 0; k < 8; ++k) We2[k] = *(const float2*)(We + k * 128 + c);
    float2 att2 = *(const float2*)(att + c);
    float2 b2   = *(const float2*)(bias + c);
    float2 xr2  = *(const float2*)(xr + (size_t)d * 128 + c);

    float2 acc = {0.f, 0.f};
    float den = 0.f, mrun = -INFINITY;

    // per-lane partial logit for one edge
    auto logit = [&](float2 xls, float4 a0, float4 a1) -> float {
        float mx = xls.x + xr2.x, my = xls.y + xr2.y;
        mx += a0.x * We2[0].x + a0.y * We2[1].x + a0.z * We2[2].x + a0.w * We2[3].x
            + a1.x * We2[4].x + a1.y * We2[5].x + a1.z * We2[6].x + a1.w * We2[7].x;
        my += a0.x * We2[0].y + a0.y * We2[1].y + a0.z * We2[2].y + a0.w * We2[3].y
            + a1.x * We2[4].y + a1.y * We2[5].y + a1.z * We2[6].y + a1.w * We2[7].y;
        mx = mx > 0.f ? mx : 0.2f * mx;
        my = my > 0.f ? my : 0.2f * my;
        return mx * att2.x + my * att2.y;
    };
    auto update = [&](float tt, float2 xls) {
        float nm = fmaxf(mrun, tt);
        float sc = __expf(mrun - nm);
        float p  = __expf(tt - nm);
        den = den * sc + p;
        acc.x = acc.x * sc + p * xls.x;
        acc.y = acc.y * sc + p * xls.y;
        mrun = nm;
    };

    int e0 = row_start[d], e1 = row_start[d + 1];
    int i = e0;
    for (; i + 4 <= e1; i += 4) {
        int ei0 = csr_eid[i], ei1 = csr_eid[i + 1], ei2 = csr_eid[i + 2], ei3 = csr_eid[i + 3];
        int s0 = srcv[ei0], s1 = srcv[ei1], s2 = srcv[ei2], s3 = srcv[ei3];
        float2 x0 = *(const float2*)(xl + (size_t)s0 * 128 + c);
        float2 x1 = *(const float2*)(xl + (size_t)s1 * 128 + c);
        float2 x2 = *(const float2*)(xl + (size_t)s2 * 128 + c);
        float2 x3 = *(const float2*)(xl + (size_t)s3 * 128 + c);
        float4 a00 = *(const float4*)(eattr + (size_t)ei0 * 8);
        float4 a01 = *(const float4*)(eattr + (size_t)ei0 * 8 + 4);
        float4 a10 = *(const float4*)(eattr + (size_t)ei1 * 8);
        float4 a11 = *(const float4*)(eattr + (size_t)ei1 * 8 + 4);
        float4 a20 = *(const float4*)(eattr + (size_t)ei2 * 8);
        float4 a21 = *(const float4*)(eattr + (size_t)ei2 * 8 + 4);
        float4 a30 = *(const float4*)(eattr + (size_t)ei3 * 8);
        float4 a31 = *(const float4*)(eattr + (size_t)ei3 * 8 + 4);
        float t0 = logit(x0, a00, a01);
        float t1 = logit(x1, a10, a11);
        float t2 = logit(x2, a20, a21);
        float t3 = logit(x3, a30, a31);
        #pragma unroll
        for (int off = 32; off; off >>= 1) {
            t0 += __shfl_xor(t0, off, 64);
            t1 += __shfl_xor(t1, off, 64);
            t2 += __shfl_xor(t2, off, 64);
            t3 += __shfl_xor(t3, off, 64);
        }
        update(t0, x0); update(t1, x1); update(t2, x2); update(t3, x3);
    }
    for (; i < e1; ++i) {
        int eid = csr_eid[i];
        int s = srcv[eid];
        float2 xls = *(const float2*)(xl + (size_t)s * 128 + c);
        float4 a0 = *(const float4*)(eattr + (size_t)eid * 8);
        float4 a1 = *(const float4*)(eattr + (size_t)eid * 8 + 4);
        float tt = logit(xls, a0, a1);
        #pragma unroll
        for (int off = 32; off; off >>= 1) tt += __shfl_xor(tt, off, 64);
        update(tt, xls);
    }

    float inv = 1.f / fmaxf(den, 1e-16f);
    float ox = acc.x * inv + b2.x;
    float oy = acc.y * inv + b2.y;
    if (RELU) { ox = fmaxf(ox, 0.f); oy = fmaxf(oy, 0.f); }
    float ss = ox * ox + oy * oy;
    #pragma unroll
    for (int off = 32; off; off >>= 1) ss += __shfl_xor(ss, off, 64);
    float nrm = sqrtf(ss);
    float innv = 1.f / fmaxf(nrm, 1e-12f);
    out[(size_t)d * 128 + c]     = ox * innv;
    out[(size_t)d * 128 + c + 1] = oy * innv;
}

// ---------------- launch ----------------

extern "C" void kernel_launch(void* const* d_in, const int* in_sizes, int n_in,
                              void* d_out, int out_size, void* d_ws, size_t ws_size,
                              hipStream_t stream) {
    const float* x_artist = (const float*)d_in[0];
    const float* x_style  = (const float*)d_in[1];
    const int*   src_aa   = (const int*)d_in[2];
    const int*   dst_aa   = (const int*)d_in[3];
    const float* eattr_aa = (const float*)d_in[4];
    const int*   src_as   = (const int*)d_in[5];
    const int*   dst_as   = (const int*)d_in[6];
    const float* eattr_as = (const float*)d_in[7];
    const float* Wl0_aa = (const float*)d_in[8];
    const float* Wr0_aa = (const float*)d_in[9];
    const float* att0_aa = (const float*)d_in[10];
    const float* We0_aa = (const float*)d_in[11];
    const float* b0_aa = (const float*)d_in[12];
    const float* Wl0_as = (const float*)d_in[13];
    const float* Wr0_as = (const float*)d_in[14];
    const float* att0_as = (const float*)d_in[15];
    const float* We0_as = (const float*)d_in[16];
    const float* b0_as = (const float*)d_in[17];
    const float* Wl_aa = (const float*)d_in[18];
    const float* Wr_aa = (const float*)d_in[19];
    const float* att_aa = (const float*)d_in[20];
    const float* We_aa = (const float*)d_in[21];
    const float* b_aa = (const float*)d_in[22];
    const float* Wl_as = (const float*)d_in[23];
    const float* Wr_as = (const float*)d_in[24];
    const float* att_as = (const float*)d_in[25];
    const float* We_as = (const float*)d_in[26];
    const float* b_as = (const float*)d_in[27];

    float* out = (float*)d_out;

    size_t off = 0;
    auto allocf = [&](size_t n) { float* r = (float*)d_ws + off; off += n; return r; };
    float* hA0 = allocf((size_t)NA * CDIM);
    float* hA1 = allocf((size_t)NA * CDIM);
    float* hS0 = allocf((size_t)NS * CDIM);
    float* hS1 = allocf((size_t)NS * CDIM);
    float* bufA = allocf((size_t)NA * CDIM);   // xl_aa
    float* bufB = allocf((size_t)NA * CDIM);   // xr_aa
    float* bufD = allocf((size_t)NA * CDIM);   // xl_as
    float* bufC = allocf((size_t)NS * CDIM);   // xr_as
    int* ip = (int*)((float*)d_ws + off);
    int* rs_aa  = ip;            ip += NA + 1;
    int* cur_aa = ip;            ip += NA;
    int* csr_aa = ip;            ip += E_AA;
    int* rs_as  = ip;            ip += NS + 1;
    int* cur_as = ip;            ip += NS;
    int* csr_as = ip;            ip += E_AS;

    hipMemsetAsync(cur_aa, 0, NA * sizeof(int), stream);
    count_k<<<(E_AA + 255) / 256, 256, 0, stream>>>(dst_aa, E_AA, cur_aa);
    scan_k<<<1, 1024, 0, stream>>>(cur_aa, rs_aa, NA);
    hipMemsetAsync(cur_aa, 0, NA * sizeof(int), stream);
    scatter_k<<<(E_AA + 255) / 256, 256, 0, stream>>>(dst_aa, E_AA, rs_aa, cur_aa, csr_aa);

    hipMemsetAsync(cur_as, 0, NS * sizeof(int), stream);
    count_k<<<(E_AS + 255) / 256, 256, 0, stream>>>(dst_as, E_AS, cur_as);
    scan_k<<<1, 1024, 0, stream>>>(cur_as, rs_as, NS);
    hipMemsetAsync(cur_as, 0, NS * sizeof(int), stream);
    scatter_k<<<(E_AS + 255) / 256, 256, 0, stream>>>(dst_as, E_AS, rs_as, cur_as, csr_as);

    const int gA = (NA + 31) / 32;
    const int gS = (NS + 31) / 32;
    const int aggA = (NA + 3) / 4;
    const int aggS = (NS + 3) / 4;

    const float* hA_in = x_artist;
    const float* hS_in = x_style;

    for (int layer = 0; layer < 3; ++layer) {
        int j = layer - 1;
        const float *pWl_aa, *pWr_aa, *patt_aa, *pWe_aa, *pb_aa;
        const float *pWl_as, *pWr_as, *patt_as, *pWe_as, *pb_as;
        if (layer == 0) {
            pWl_aa = Wl0_aa; pWr_aa = Wr0_aa; patt_aa = att0_aa; pWe_aa = We0_aa; pb_aa = b0_aa;
            pWl_as = Wl0_as; pWr_as = Wr0_as; patt_as = att0_as; pWe_as = We0_as; pb_as = b0_as;
        } else {
            pWl_aa = Wl_aa + (size_t)j * CDIM * CDIM;
            pWr_aa = Wr_aa + (size_t)j * CDIM * CDIM;
            patt_aa = att_aa + (size_t)j * CDIM;
            pWe_aa = We_aa + (size_t)j * ED * CDIM;
            pb_aa = b_aa + (size_t)j * CDIM;
            pWl_as = Wl_as + (size_t)j * CDIM * CDIM;
            pWr_as = Wr_as + (size_t)j * CDIM * CDIM;
            patt_as = att_as + (size_t)j * CDIM;
            pWe_as = We_as + (size_t)j * ED * CDIM;
            pb_as = b_as + (size_t)j * CDIM;
        }
        float* hA_out = (layer == 2) ? out : (layer == 0 ? hA0 : hA1);
        float* hS_out = (layer == 2) ? out + (size_t)NA * CDIM : (layer == 0 ? hS0 : hS1);

        // all three hA-consuming GEMMs fused (DIN_A == C == 128 every layer)
        gemm3_k<<<gA, 256, 0, stream>>>(hA_in, pWl_aa, pWr_aa, pWl_as,
                                        bufA, bufB, bufD, NA);
        if (layer == 0)
            gemm_k<64><<<gS, 256, 0, stream>>>(hS_in, pWr_as, bufC, NS);
        else
            gemm_k<128><<<gS, 256, 0, stream>>>(hS_in, pWr_as, bufC, NS);

        if (layer < 2) {
            agg_k<true><<<aggA, 256, 0, stream>>>(bufA, bufB, eattr_aa, src_aa, pWe_aa,
                                                  patt_aa, pb_aa, rs_aa, csr_aa, hA_out, NA);
            agg_k<true><<<aggS, 256, 0, stream>>>(bufD, bufC, eattr_as, src_as, pWe_as,
                                                  patt_as, pb_as, rs_as, csr_as, hS_out, NS);
        } else {
            agg_k<false><<<aggA, 256, 0, stream>>>(bufA, bufB, eattr_aa, src_aa, pWe_aa,
                                                   patt_aa, pb_aa, rs_aa, csr_aa, hA_out, NA);
            agg_k<false><<<aggS, 256, 0, stream>>>(bufD, bufC, eattr_as, src_as, pWe_as,
                                                   patt_as, pb_as, rs_as, csr_as, hS_out, NS);
        }

        hA_in = hA_out;
        hS_in = hS_out;
    }
}